// Round 6
// baseline (82.068 us; speedup 1.0000x reference)
//
#include <hip/hip_runtime.h>

// KFIoU loss: per-row 5-float (x,y,w,h,r) pred/target -> smooth-L1 xy loss +
// KF IoU loss. Outputs: [loss.mean, xy_loss.mean, kf_loss.mean, KFIoU*3 (N)].
//
// R1: same-address atomic storm -> partials + reduce kernel.       (80us)
// R2: row-quad float4 loads.                                       (24.4us)
// R3: LDS staging regressed.                                       (26.9us)
// R4: 20B/lane dwordx4+dword loads == R2 -> loads not limiter.     (23.8us)
// R5: hw trig on 2r + det identity (Vb=0.25*Vp*Vt*rsqrt(detSum));
//     compute not the limiter either.                              (22.8us)
// R6: fuse final reduce via last-block. Winner = block whose
//     atomicAdd old-value == 2047 (mod 2048): works for ANY initial
//     counter value (poison-proof, no memset node). Agent-scope
//     atomics for cross-XCD partials visibility (G16).

#define NBLK  2048   // must be power of 2 for the mod-window winner trick
#define BLOCK 256

__device__ __forceinline__ void cov_terms(float w, float h, float r,
                                          float& s11, float& s12, float& s22,
                                          float& V) {
    w = fminf(fmaxf(w, 1e-7f), 1e7f);
    h = fminf(fmaxf(h, 1e-7f), 1e7f);
    const float sw = 0.25f * w * w;        // (0.5*w)^2
    const float sh = 0.25f * h * h;
    const float htr = 0.5f * (sw + sh);
    const float hdf = 0.5f * (sw - sh);
    // s11 = htr + cos(2r)*hdf ; s22 = htr - cos(2r)*hdf ; s12 = sin(2r)*hdf
    // hw trig computes sin(2*pi*x); 2r -> x = r/pi, |x|<=1.3: in range.
    const float x = r * 0.3183098861837907f;
    const float s2 = __builtin_amdgcn_sinf(x);
    const float c2 = __builtin_amdgcn_cosf(x);
    s11 = fmaf(c2, hdf, htr);
    s22 = fmaf(-c2, hdf, htr);
    s12 = s2 * hdf;
    V = w * h;
}

__device__ __forceinline__ float kf_row(const float* P, const float* T,
                                        float& xyl, float& kfl) {
    const float dx = fabsf(P[0] - T[0]);
    const float dy = fabsf(P[1] - T[1]);
    const float lx = dx < 1.0f ? 0.5f * dx * dx : dx - 0.5f;
    const float ly = dy < 1.0f ? 0.5f * dy * dy : dy - 0.5f;
    xyl = lx + ly;

    float ap, bp, dp, Vp, at, bt, dt, Vt;
    cov_terms(P[2], P[3], P[4], ap, bp, dp, Vp);
    cov_terms(T[2], T[3], T[4], at, bt, dt, Vt);

    // Sigma = Sp(Sp+St)^-1 St => detS = detSp*detSt/detSum, detSp=(Vp/4)^2
    // => Vb = 4*sqrt(detS) = 0.25*Vp*Vt*rsqrt(detSum)
    const float A = ap + at, B = bp + bt, D = dp + dt;
    const float detSum = fmaf(A, D, -B * B);
    const float Vb = (detSum > 0.0f)
                         ? 0.25f * Vp * Vt * __builtin_amdgcn_rsqf(detSum)
                         : 0.0f;
    const float kfiou = Vb * __builtin_amdgcn_rcpf(Vp + Vt - Vb + 1e-6f);
    kfl = 1.0f - kfiou;
    return 3.0f * kfiou;
}

__global__ __launch_bounds__(BLOCK) void kf_main(
    const float* __restrict__ pred, const float* __restrict__ tgt,
    float* __restrict__ out, float* __restrict__ ws, int n, double invn)
{
    float* partials = ws;                 // [3][NBLK]
    unsigned int* counter = (unsigned int*)(ws + 3 * NBLK);

    const int stride = gridDim.x * blockDim.x;
    float sl = 0.f, sx = 0.f, sk = 0.f;

    for (int i = blockIdx.x * blockDim.x + threadIdx.x; i < n; i += stride) {
        const float* p = pred + 5 * (size_t)i;
        const float* t = tgt  + 5 * (size_t)i;
        float P[5], T[5];
        __builtin_memcpy(P, p, 16);  P[4] = p[4];   // dwordx4 + dword
        __builtin_memcpy(T, t, 16);  T[4] = t[4];

        float xyl, kfl;
        const float k3 = kf_row(P, T, xyl, kfl);
        out[3 + (size_t)i] = k3;
        sl += fmaxf(xyl + kfl, 0.f);
        sx += xyl;
        sk += kfl;
    }

    // wave64 tree reduce (fp32)
#pragma unroll
    for (int off = 32; off > 0; off >>= 1) {
        sl += __shfl_down(sl, off);
        sx += __shfl_down(sx, off);
        sk += __shfl_down(sk, off);
    }
    __shared__ float smem[3][4];
    const int lane = threadIdx.x & 63;
    const int wave = threadIdx.x >> 6;
    if (lane == 0) {
        smem[0][wave] = sl; smem[1][wave] = sx; smem[2][wave] = sk;
    }
    __syncthreads();

    __shared__ int is_winner;
    if (threadIdx.x == 0) {
        float a = 0, b = 0, c = 0;
#pragma unroll
        for (int w = 0; w < 4; ++w) { a += smem[0][w]; b += smem[1][w]; c += smem[2][w]; }
        // agent-scope stores: visible device-wide at the coherent point
        __hip_atomic_store(&partials[blockIdx.x],            a,
                           __ATOMIC_RELAXED, __HIP_MEMORY_SCOPE_AGENT);
        __hip_atomic_store(&partials[NBLK + blockIdx.x],     b,
                           __ATOMIC_RELAXED, __HIP_MEMORY_SCOPE_AGENT);
        __hip_atomic_store(&partials[2 * NBLK + blockIdx.x], c,
                           __ATOMIC_RELAXED, __HIP_MEMORY_SCOPE_AGENT);
        // free-running counter: one dispatch adds a window of NBLK consecutive
        // values -> exactly one block sees old ≡ NBLK-1 (mod NBLK), for ANY
        // initial value (poison-proof, survives wraparound).
        const unsigned int old = __hip_atomic_fetch_add(
            counter, 1u, __ATOMIC_ACQ_REL, __HIP_MEMORY_SCOPE_AGENT);
        is_winner = ((old & (NBLK - 1)) == (NBLK - 1));
    }
    __syncthreads();

    if (is_winner) {
        double a = 0, b = 0, c = 0;
        for (int i = threadIdx.x; i < NBLK; i += BLOCK) {   // fixed order: deterministic
            a += (double)__hip_atomic_load(&partials[i],
                     __ATOMIC_RELAXED, __HIP_MEMORY_SCOPE_AGENT);
            b += (double)__hip_atomic_load(&partials[NBLK + i],
                     __ATOMIC_RELAXED, __HIP_MEMORY_SCOPE_AGENT);
            c += (double)__hip_atomic_load(&partials[2 * NBLK + i],
                     __ATOMIC_RELAXED, __HIP_MEMORY_SCOPE_AGENT);
        }
#pragma unroll
        for (int off = 32; off > 0; off >>= 1) {
            a += __shfl_down(a, off);
            b += __shfl_down(b, off);
            c += __shfl_down(c, off);
        }
        __shared__ double dmem[3][4];
        if (lane == 0) {
            dmem[0][wave] = a; dmem[1][wave] = b; dmem[2][wave] = c;
        }
        __syncthreads();
        if (threadIdx.x == 0) {
            double ra = 0, rb = 0, rc = 0;
#pragma unroll
            for (int w = 0; w < 4; ++w) { ra += dmem[0][w]; rb += dmem[1][w]; rc += dmem[2][w]; }
            out[0] = (float)(ra * invn);
            out[1] = (float)(rb * invn);
            out[2] = (float)(rc * invn);
        }
    }
}

extern "C" void kernel_launch(void* const* d_in, const int* in_sizes, int n_in,
                              void* d_out, int out_size, void* d_ws, size_t ws_size,
                              hipStream_t stream) {
    const float* pred = (const float*)d_in[0];
    const float* tgt  = (const float*)d_in[1];
    float* out = (float*)d_out;
    float* ws  = (float*)d_ws;    // 3*NBLK partials + 1 counter

    const int n = in_sizes[0] / 5;    // 2,000,000

    kf_main<<<NBLK, BLOCK, 0, stream>>>(pred, tgt, out, ws, n, 1.0 / (double)n);
}

// Round 7
// 76.773 us; speedup vs baseline: 1.0690x; 1.0690x over previous
//
#include <hip/hip_runtime.h>

// KFIoU loss: per-row 5-float (x,y,w,h,r) pred/target -> smooth-L1 xy loss +
// KF IoU loss. Outputs: [loss.mean, xy_loss.mean, kf_loss.mean, KFIoU*3 (N)].
//
// R1: same-address atomic storm -> partials + reduce kernel.       (80us)
// R2: row-quad float4 loads.                                       (24.4us)
// R3: LDS staging regressed.                                       (26.9us)
// R4: 20B/lane dwordx4+dword loads == R2 -> loads not limiter.     (23.8us)
// R5: hw trig on 2r + det identity; compute not limiter either.    (22.8us)
// R6: last-block fusion w/ ACQ_REL agent atomics: buffer_inv storm
//     + VGPR collapse to 16 (no MLP) -> latency-bound.             (82us!)
// R7: fusion kept, but RELEASE-only fetch_add (s_waitcnt, no cache
//     inv; RMW total order makes winner see all release'd partials)
//     + hand-pipelined x2 row loop to force MLP regardless of
//     regalloc mood.

#define NBLK  2048   // power of 2: winner = (old mod NBLK)==NBLK-1, any init
#define BLOCK 256

__device__ __forceinline__ void cov_terms(float w, float h, float r,
                                          float& s11, float& s12, float& s22,
                                          float& V) {
    w = fminf(fmaxf(w, 1e-7f), 1e7f);
    h = fminf(fmaxf(h, 1e-7f), 1e7f);
    const float sw = 0.25f * w * w;        // (0.5*w)^2
    const float sh = 0.25f * h * h;
    const float htr = 0.5f * (sw + sh);
    const float hdf = 0.5f * (sw - sh);
    // s11 = htr + cos(2r)*hdf ; s22 = htr - cos(2r)*hdf ; s12 = sin(2r)*hdf
    // hw trig computes sin(2*pi*x); 2r -> x = r/pi, |x|<=1.3: in range.
    const float x = r * 0.3183098861837907f;
    const float s2 = __builtin_amdgcn_sinf(x);
    const float c2 = __builtin_amdgcn_cosf(x);
    s11 = fmaf(c2, hdf, htr);
    s22 = fmaf(-c2, hdf, htr);
    s12 = s2 * hdf;
    V = w * h;
}

__device__ __forceinline__ float kf_row(const float* P, const float* T,
                                        float& xyl, float& kfl) {
    const float dx = fabsf(P[0] - T[0]);
    const float dy = fabsf(P[1] - T[1]);
    const float lx = dx < 1.0f ? 0.5f * dx * dx : dx - 0.5f;
    const float ly = dy < 1.0f ? 0.5f * dy * dy : dy - 0.5f;
    xyl = lx + ly;

    float ap, bp, dp, Vp, at, bt, dt, Vt;
    cov_terms(P[2], P[3], P[4], ap, bp, dp, Vp);
    cov_terms(T[2], T[3], T[4], at, bt, dt, Vt);

    // Sigma = Sp(Sp+St)^-1 St => detS = detSp*detSt/detSum, detSp=(Vp/4)^2
    // => Vb = 4*sqrt(detS) = 0.25*Vp*Vt*rsqrt(detSum)
    const float A = ap + at, B = bp + bt, D = dp + dt;
    const float detSum = fmaf(A, D, -B * B);
    const float Vb = (detSum > 0.0f)
                         ? 0.25f * Vp * Vt * __builtin_amdgcn_rsqf(detSum)
                         : 0.0f;
    const float kfiou = Vb * __builtin_amdgcn_rcpf(Vp + Vt - Vb + 1e-6f);
    kfl = 1.0f - kfiou;
    return 3.0f * kfiou;
}

__device__ __forceinline__ void load_row(const float* __restrict__ base,
                                         int i, float* R) {
    const float* q = base + 5 * (size_t)i;
    __builtin_memcpy(R, q, 16);   // dwordx4 (dword-aligned OK on gfx9+)
    R[4] = q[4];                  // + dword
}

__global__ __launch_bounds__(BLOCK) void kf_main(
    const float* __restrict__ pred, const float* __restrict__ tgt,
    float* __restrict__ out, float* __restrict__ ws, int n, double invn)
{
    float* partials = ws;                 // [3][NBLK]
    unsigned int* counter = (unsigned int*)(ws + 3 * NBLK);

    const int stride = gridDim.x * blockDim.x;
    const int gid = blockIdx.x * blockDim.x + threadIdx.x;
    float sl = 0.f, sx = 0.f, sk = 0.f;

    // hand-pipelined x2: both rows' loads issue before either compute -> MLP
    int i = gid;
    for (; i + stride < n; i += 2 * stride) {
        float P0[5], T0[5], P1[5], T1[5];
        load_row(pred, i, P0);
        load_row(tgt,  i, T0);
        load_row(pred, i + stride, P1);
        load_row(tgt,  i + stride, T1);

        float xyl0, kfl0, xyl1, kfl1;
        const float a0 = kf_row(P0, T0, xyl0, kfl0);
        const float a1 = kf_row(P1, T1, xyl1, kfl1);
        out[3 + (size_t)i]            = a0;
        out[3 + (size_t)(i + stride)] = a1;
        sl += fmaxf(xyl0 + kfl0, 0.f) + fmaxf(xyl1 + kfl1, 0.f);
        sx += xyl0 + xyl1;
        sk += kfl0 + kfl1;
    }
    for (; i < n; i += stride) {
        float P[5], T[5];
        load_row(pred, i, P);
        load_row(tgt,  i, T);
        float xyl, kfl;
        const float k3 = kf_row(P, T, xyl, kfl);
        out[3 + (size_t)i] = k3;
        sl += fmaxf(xyl + kfl, 0.f);
        sx += xyl;
        sk += kfl;
    }

    // wave64 tree reduce (fp32)
#pragma unroll
    for (int off = 32; off > 0; off >>= 1) {
        sl += __shfl_down(sl, off);
        sx += __shfl_down(sx, off);
        sk += __shfl_down(sk, off);
    }
    __shared__ float smem[3][4];
    const int lane = threadIdx.x & 63;
    const int wave = threadIdx.x >> 6;
    if (lane == 0) {
        smem[0][wave] = sl; smem[1][wave] = sx; smem[2][wave] = sk;
    }
    __syncthreads();

    __shared__ int is_winner;
    if (threadIdx.x == 0) {
        float a = 0, b = 0, c = 0;
#pragma unroll
        for (int w = 0; w < 4; ++w) { a += smem[0][w]; b += smem[1][w]; c += smem[2][w]; }
        // write-through (agent-scope atomic) stores: land at coherence point
        __hip_atomic_store(&partials[blockIdx.x],            a,
                           __ATOMIC_RELAXED, __HIP_MEMORY_SCOPE_AGENT);
        __hip_atomic_store(&partials[NBLK + blockIdx.x],     b,
                           __ATOMIC_RELAXED, __HIP_MEMORY_SCOPE_AGENT);
        __hip_atomic_store(&partials[2 * NBLK + blockIdx.x], c,
                           __ATOMIC_RELAXED, __HIP_MEMORY_SCOPE_AGENT);
        // RELEASE: s_waitcnt vmcnt(0) before the RMW, no cache invalidate.
        // RMW total order => block seeing old≡NBLK-1 knows all 2047 prior
        // release-adds (and thus their partials) reached coherence point.
        const unsigned int old = __hip_atomic_fetch_add(
            counter, 1u, __ATOMIC_RELEASE, __HIP_MEMORY_SCOPE_AGENT);
        is_winner = ((old & (NBLK - 1)) == (NBLK - 1));
    }
    __syncthreads();

    if (is_winner) {
        double a = 0, b = 0, c = 0;
        for (int j = threadIdx.x; j < NBLK; j += BLOCK) {   // fixed order: deterministic
            a += (double)__hip_atomic_load(&partials[j],
                     __ATOMIC_RELAXED, __HIP_MEMORY_SCOPE_AGENT);
            b += (double)__hip_atomic_load(&partials[NBLK + j],
                     __ATOMIC_RELAXED, __HIP_MEMORY_SCOPE_AGENT);
            c += (double)__hip_atomic_load(&partials[2 * NBLK + j],
                     __ATOMIC_RELAXED, __HIP_MEMORY_SCOPE_AGENT);
        }
#pragma unroll
        for (int off = 32; off > 0; off >>= 1) {
            a += __shfl_down(a, off);
            b += __shfl_down(b, off);
            c += __shfl_down(c, off);
        }
        __shared__ double dmem[3][4];
        if (lane == 0) {
            dmem[0][wave] = a; dmem[1][wave] = b; dmem[2][wave] = c;
        }
        __syncthreads();
        if (threadIdx.x == 0) {
            double ra = 0, rb = 0, rc = 0;
#pragma unroll
            for (int w = 0; w < 4; ++w) { ra += dmem[0][w]; rb += dmem[1][w]; rc += dmem[2][w]; }
            out[0] = (float)(ra * invn);
            out[1] = (float)(rb * invn);
            out[2] = (float)(rc * invn);
        }
    }
}

extern "C" void kernel_launch(void* const* d_in, const int* in_sizes, int n_in,
                              void* d_out, int out_size, void* d_ws, size_t ws_size,
                              hipStream_t stream) {
    const float* pred = (const float*)d_in[0];
    const float* tgt  = (const float*)d_in[1];
    float* out = (float*)d_out;
    float* ws  = (float*)d_ws;    // 3*NBLK partials + 1 counter

    const int n = in_sizes[0] / 5;    // 2,000,000

    kf_main<<<NBLK, BLOCK, 0, stream>>>(pred, tgt, out, ws, n, 1.0 / (double)n);
}

// Round 8
// 38.580 us; speedup vs baseline: 2.1272x; 1.9900x over previous
//
#include <hip/hip_runtime.h>

// KFIoU loss: per-row 5-float (x,y,w,h,r) pred/target -> smooth-L1 xy loss +
// KF IoU loss. Outputs: [loss.mean, xy_loss.mean, kf_loss.mean, KFIoU*3 (N)].
//
// R1: same-address atomic storm -> partials + reduce kernel.       (80us)
// R2: row-quad float4 loads.                                       (24.4us)
// R3: LDS staging regressed.                                       (26.9us)
// R4: 20B/lane dwordx4+dword loads == R2 -> loads not limiter.     (23.8us)
// R5: hw trig on 2r + det identity; compute not limiter either.    (22.8us)
// R6: fused tail, ACQ_REL agent: buffer_inv+wbl2 per block.        (82us!)
// R7: RELEASE agent: still buffer_wbl2 per block -> same storm;
//     warm replays 100us @ 90GB/s, VALU 3.6% = idle on L2 flushes. (77us!)
// R8: fusion with ZERO cache-maintenance ops: partials via relaxed
//     agent atomic_exchange (RMW performs at MALL, no dirty L2),
//     inline s_waitcnt vmcnt(0) (exchange acks counted), RELAXED
//     fetch_add counter (no wbl2). RMW total order => winner sees
//     all partials performed. Winner reads via relaxed agent loads.

#define NBLK  2048   // power of 2: winner = (old mod NBLK)==NBLK-1, any init
#define BLOCK 256

__device__ __forceinline__ void cov_terms(float w, float h, float r,
                                          float& s11, float& s12, float& s22,
                                          float& V) {
    w = fminf(fmaxf(w, 1e-7f), 1e7f);
    h = fminf(fmaxf(h, 1e-7f), 1e7f);
    const float sw = 0.25f * w * w;        // (0.5*w)^2
    const float sh = 0.25f * h * h;
    const float htr = 0.5f * (sw + sh);
    const float hdf = 0.5f * (sw - sh);
    // s11 = htr + cos(2r)*hdf ; s22 = htr - cos(2r)*hdf ; s12 = sin(2r)*hdf
    // hw trig computes sin(2*pi*x); 2r -> x = r/pi, |x|<=1.3: in range.
    const float x = r * 0.3183098861837907f;
    const float s2 = __builtin_amdgcn_sinf(x);
    const float c2 = __builtin_amdgcn_cosf(x);
    s11 = fmaf(c2, hdf, htr);
    s22 = fmaf(-c2, hdf, htr);
    s12 = s2 * hdf;
    V = w * h;
}

__device__ __forceinline__ float kf_row(const float* P, const float* T,
                                        float& xyl, float& kfl) {
    const float dx = fabsf(P[0] - T[0]);
    const float dy = fabsf(P[1] - T[1]);
    const float lx = dx < 1.0f ? 0.5f * dx * dx : dx - 0.5f;
    const float ly = dy < 1.0f ? 0.5f * dy * dy : dy - 0.5f;
    xyl = lx + ly;

    float ap, bp, dp, Vp, at, bt, dt, Vt;
    cov_terms(P[2], P[3], P[4], ap, bp, dp, Vp);
    cov_terms(T[2], T[3], T[4], at, bt, dt, Vt);

    // Sigma = Sp(Sp+St)^-1 St => detS = detSp*detSt/detSum, detSp=(Vp/4)^2
    // => Vb = 4*sqrt(detS) = 0.25*Vp*Vt*rsqrt(detSum)
    const float A = ap + at, B = bp + bt, D = dp + dt;
    const float detSum = fmaf(A, D, -B * B);
    const float Vb = (detSum > 0.0f)
                         ? 0.25f * Vp * Vt * __builtin_amdgcn_rsqf(detSum)
                         : 0.0f;
    const float kfiou = Vb * __builtin_amdgcn_rcpf(Vp + Vt - Vb + 1e-6f);
    kfl = 1.0f - kfiou;
    return 3.0f * kfiou;
}

__global__ __launch_bounds__(BLOCK) void kf_main(
    const float* __restrict__ pred, const float* __restrict__ tgt,
    float* __restrict__ out, float* __restrict__ ws, int n, double invn)
{
    float* partials = ws;                 // [3][NBLK]
    unsigned int* counter = (unsigned int*)(ws + 3 * NBLK);

    const int stride = gridDim.x * blockDim.x;
    float sl = 0.f, sx = 0.f, sk = 0.f;

    // R5's known-good main loop, unchanged
    for (int i = blockIdx.x * blockDim.x + threadIdx.x; i < n; i += stride) {
        const float* p = pred + 5 * (size_t)i;
        const float* t = tgt  + 5 * (size_t)i;
        float P[5], T[5];
        __builtin_memcpy(P, p, 16);  P[4] = p[4];   // dwordx4 + dword
        __builtin_memcpy(T, t, 16);  T[4] = t[4];

        float xyl, kfl;
        const float k3 = kf_row(P, T, xyl, kfl);
        out[3 + (size_t)i] = k3;
        sl += fmaxf(xyl + kfl, 0.f);
        sx += xyl;
        sk += kfl;
    }

    // wave64 tree reduce (fp32)
#pragma unroll
    for (int off = 32; off > 0; off >>= 1) {
        sl += __shfl_down(sl, off);
        sx += __shfl_down(sx, off);
        sk += __shfl_down(sk, off);
    }
    __shared__ float smem[3][4];
    const int lane = threadIdx.x & 63;
    const int wave = threadIdx.x >> 6;
    if (lane == 0) {
        smem[0][wave] = sl; smem[1][wave] = sx; smem[2][wave] = sk;
    }
    __syncthreads();

    __shared__ int is_winner;
    if (threadIdx.x == 0) {
        float a = 0, b = 0, c = 0;
#pragma unroll
        for (int w = 0; w < 4; ++w) { a += smem[0][w]; b += smem[1][w]; c += smem[2][w]; }
        // RMW exchange: performed AT the MALL coherence point -> no dirty L2
        // line, so no buffer_wbl2 is ever required (the R6/R7 lesson).
        (void)__hip_atomic_exchange(&partials[blockIdx.x],            a,
                                    __ATOMIC_RELAXED, __HIP_MEMORY_SCOPE_AGENT);
        (void)__hip_atomic_exchange(&partials[NBLK + blockIdx.x],     b,
                                    __ATOMIC_RELAXED, __HIP_MEMORY_SCOPE_AGENT);
        (void)__hip_atomic_exchange(&partials[2 * NBLK + blockIdx.x], c,
                                    __ATOMIC_RELAXED, __HIP_MEMORY_SCOPE_AGENT);
        // HW completion order: exchange acks are counted in vmcnt; after this
        // wait the three RMWs are performed at MALL. "memory" = compiler fence.
        asm volatile("s_waitcnt vmcnt(0)" ::: "memory");
        // RELAXED counter RMW (plain global_atomic_add, no cache ops).
        // RMW total order on one address => the block that sees
        // old ≡ NBLK-1 (mod NBLK) knows all 2047 prior adds -- and therefore
        // their already-completed partials -- are performed. Free-running:
        // correct for ANY initial value (poison-proof, wraparound-proof).
        const unsigned int old = __hip_atomic_fetch_add(
            counter, 1u, __ATOMIC_RELAXED, __HIP_MEMORY_SCOPE_AGENT);
        is_winner = ((old & (NBLK - 1)) == (NBLK - 1));
    }
    __syncthreads();

    if (is_winner) {
        double a = 0, b = 0, c = 0;
        for (int j = threadIdx.x; j < NBLK; j += BLOCK) {   // fixed order: deterministic
            a += (double)__hip_atomic_load(&partials[j],
                     __ATOMIC_RELAXED, __HIP_MEMORY_SCOPE_AGENT);
            b += (double)__hip_atomic_load(&partials[NBLK + j],
                     __ATOMIC_RELAXED, __HIP_MEMORY_SCOPE_AGENT);
            c += (double)__hip_atomic_load(&partials[2 * NBLK + j],
                     __ATOMIC_RELAXED, __HIP_MEMORY_SCOPE_AGENT);
        }
#pragma unroll
        for (int off = 32; off > 0; off >>= 1) {
            a += __shfl_down(a, off);
            b += __shfl_down(b, off);
            c += __shfl_down(c, off);
        }
        __shared__ double dmem[3][4];
        if (lane == 0) {
            dmem[0][wave] = a; dmem[1][wave] = b; dmem[2][wave] = c;
        }
        __syncthreads();
        if (threadIdx.x == 0) {
            double ra = 0, rb = 0, rc = 0;
#pragma unroll
            for (int w = 0; w < 4; ++w) { ra += dmem[0][w]; rb += dmem[1][w]; rc += dmem[2][w]; }
            out[0] = (float)(ra * invn);
            out[1] = (float)(rb * invn);
            out[2] = (float)(rc * invn);
        }
    }
}

extern "C" void kernel_launch(void* const* d_in, const int* in_sizes, int n_in,
                              void* d_out, int out_size, void* d_ws, size_t ws_size,
                              hipStream_t stream) {
    const float* pred = (const float*)d_in[0];
    const float* tgt  = (const float*)d_in[1];
    float* out = (float*)d_out;
    float* ws  = (float*)d_ws;    // 3*NBLK partials + 1 counter

    const int n = in_sizes[0] / 5;    // 2,000,000

    kf_main<<<NBLK, BLOCK, 0, stream>>>(pred, tgt, out, ws, n, 1.0 / (double)n);
}

// Round 10
// 23.558 us; speedup vs baseline: 3.4837x; 1.6377x over previous
//
#include <hip/hip_runtime.h>

// KFIoU loss: per-row 5-float (x,y,w,h,r) pred/target -> smooth-L1 xy loss +
// KF IoU loss. Outputs: [loss.mean, xy_loss.mean, kf_loss.mean, KFIoU*3 (N)].
//
// R1: same-address atomic storm -> partials + reduce kernel.       (80us)
// R2: row-quad float4 loads.                                       (24.4us)
// R3: LDS staging regressed.                                       (26.9us)
// R4: 20B/lane dwordx4+dword == R2 -> load shape not limiter.      (23.8us)
// R5: hw trig on 2r + det identity; compute not limiter either.    (22.8us)
// R6-R9: single-kernel last-block fusion arc ABANDONED: wbl2 storm
//     (82/77us), VGPR collapse (38.6us), then a memory-model race
//     (tripwire fail). Source-level agent-atomic handshakes on
//     multi-XCD parts are not provably correct -> back to 2 kernels.
// R10: R5 structure + R9's straight-line one-quad-per-thread main
//     (10 independent float4 loads, no loop -> MLP, high VGPR) +
//     nontemporal stores for the 8MB KFIoU array.

#define BLOCK 256

__device__ __forceinline__ void cov_terms(float w, float h, float r,
                                          float& s11, float& s12, float& s22,
                                          float& V) {
    w = fminf(fmaxf(w, 1e-7f), 1e7f);
    h = fminf(fmaxf(h, 1e-7f), 1e7f);
    const float sw = 0.25f * w * w;        // (0.5*w)^2
    const float sh = 0.25f * h * h;
    const float htr = 0.5f * (sw + sh);
    const float hdf = 0.5f * (sw - sh);
    // s11 = htr + cos(2r)*hdf ; s22 = htr - cos(2r)*hdf ; s12 = sin(2r)*hdf
    // hw trig computes sin(2*pi*x); 2r -> x = r/pi, |x|<=1.3: in range.
    const float x = r * 0.3183098861837907f;
    const float s2 = __builtin_amdgcn_sinf(x);
    const float c2 = __builtin_amdgcn_cosf(x);
    s11 = fmaf(c2, hdf, htr);
    s22 = fmaf(-c2, hdf, htr);
    s12 = s2 * hdf;
    V = w * h;
}

__device__ __forceinline__ float kf_row(const float* P, const float* T,
                                        float& xyl, float& kfl) {
    const float dx = fabsf(P[0] - T[0]);
    const float dy = fabsf(P[1] - T[1]);
    const float lx = dx < 1.0f ? 0.5f * dx * dx : dx - 0.5f;
    const float ly = dy < 1.0f ? 0.5f * dy * dy : dy - 0.5f;
    xyl = lx + ly;

    float ap, bp, dp, Vp, at, bt, dt, Vt;
    cov_terms(P[2], P[3], P[4], ap, bp, dp, Vp);
    cov_terms(T[2], T[3], T[4], at, bt, dt, Vt);

    // Sigma = Sp(Sp+St)^-1 St => detS = detSp*detSt/detSum, detSp=(Vp/4)^2
    // => Vb = 4*sqrt(detS) = 0.25*Vp*Vt*rsqrt(detSum)
    const float A = ap + at, B = bp + bt, D = dp + dt;
    const float detSum = fmaf(A, D, -B * B);
    const float Vb = (detSum > 0.0f)
                         ? 0.25f * Vp * Vt * __builtin_amdgcn_rsqf(detSum)
                         : 0.0f;
    const float kfiou = Vb * __builtin_amdgcn_rcpf(Vp + Vt - Vb + 1e-6f);
    kfl = 1.0f - kfiou;
    return 3.0f * kfiou;
}

__global__ __launch_bounds__(BLOCK) void kf_main(
    const float4* __restrict__ pred4, const float4* __restrict__ tgt4,
    float* __restrict__ out, float* __restrict__ partials, int n)
{
    const int n4 = n >> 2;                       // row-quads
    const int t  = blockIdx.x * BLOCK + threadIdx.x;
    float sl = 0.f, sx = 0.f, sk = 0.f;

    if (t < n4) {
        // straight-line: 10 independent float4 loads issued before any use
        float P[20], T[20];
        const float4* p4 = pred4 + 5 * (size_t)t;
        const float4* t4 = tgt4  + 5 * (size_t)t;
#pragma unroll
        for (int j = 0; j < 5; ++j) reinterpret_cast<float4*>(P)[j] = p4[j];
#pragma unroll
        for (int j = 0; j < 5; ++j) reinterpret_cast<float4*>(T)[j] = t4[j];

#pragma unroll
        for (int k = 0; k < 4; ++k) {
            float xyl, kfl;
            const float k3 = kf_row(P + 5 * k, T + 5 * k, xyl, kfl);
            // never re-read in-kernel: nt store keeps input lines cached
            __builtin_nontemporal_store(k3, &out[3 + 4 * (size_t)t + k]);
            sl += fmaxf(xyl + kfl, 0.f);
            sx += xyl;
            sk += kfl;
        }
    }
    // leftover rows (n % 4) — dead for N=2M, kept for generality
    const int ri = (n4 << 2) + t;
    if (ri < n) {
        const float* p = (const float*)pred4 + 5 * (size_t)ri;
        const float* q = (const float*)tgt4  + 5 * (size_t)ri;
        float P[5], T[5];
#pragma unroll
        for (int j = 0; j < 5; ++j) { P[j] = p[j]; T[j] = q[j]; }
        float xyl, kfl;
        const float k3 = kf_row(P, T, xyl, kfl);
        __builtin_nontemporal_store(k3, &out[3 + (size_t)ri]);
        sl += fmaxf(xyl + kfl, 0.f);
        sx += xyl;
        sk += kfl;
    }

    // wave64 tree reduce (fp32)
#pragma unroll
    for (int off = 32; off > 0; off >>= 1) {
        sl += __shfl_down(sl, off);
        sx += __shfl_down(sx, off);
        sk += __shfl_down(sk, off);
    }
    __shared__ float smem[3][4];
    const int lane = threadIdx.x & 63;
    const int wave = threadIdx.x >> 6;
    if (lane == 0) {
        smem[0][wave] = sl; smem[1][wave] = sx; smem[2][wave] = sk;
    }
    __syncthreads();
    if (threadIdx.x == 0) {
        float a = 0, b = 0, c = 0;
#pragma unroll
        for (int w = 0; w < 4; ++w) { a += smem[0][w]; b += smem[1][w]; c += smem[2][w]; }
        const int np = gridDim.x;                // plain stores; next dispatch
        partials[blockIdx.x]          = a;       // sees them (stream ordering)
        partials[np + blockIdx.x]     = b;
        partials[2 * np + blockIdx.x] = c;
    }
}

__global__ __launch_bounds__(1024) void kf_reduce(
    const float* __restrict__ partials, float* __restrict__ out,
    int npart, double invn)
{
    double a = 0, b = 0, c = 0;
    for (int i = threadIdx.x; i < npart; i += 1024) {
        a += (double)partials[i];
        b += (double)partials[npart + i];
        c += (double)partials[2 * npart + i];
    }
#pragma unroll
    for (int off = 32; off > 0; off >>= 1) {
        a += __shfl_down(a, off);
        b += __shfl_down(b, off);
        c += __shfl_down(c, off);
    }
    __shared__ double smem[3][16];
    const int lane = threadIdx.x & 63;
    const int wave = threadIdx.x >> 6;
    if (lane == 0) {
        smem[0][wave] = a; smem[1][wave] = b; smem[2][wave] = c;
    }
    __syncthreads();
    if (threadIdx.x == 0) {
        double ra = 0, rb = 0, rc = 0;
#pragma unroll
        for (int w = 0; w < 16; ++w) { ra += smem[0][w]; rb += smem[1][w]; rc += smem[2][w]; }
        out[0] = (float)(ra * invn);
        out[1] = (float)(rb * invn);
        out[2] = (float)(rc * invn);
    }
}

extern "C" void kernel_launch(void* const* d_in, const int* in_sizes, int n_in,
                              void* d_out, int out_size, void* d_ws, size_t ws_size,
                              hipStream_t stream) {
    const float4* pred4 = (const float4*)d_in[0];
    const float4* tgt4  = (const float4*)d_in[1];
    float* out = (float*)d_out;
    float* partials = (float*)d_ws;

    const int n  = in_sizes[0] / 5;              // 2,000,000
    const int n4 = n >> 2;                       // 500,000
    const int nblocks = (n4 + BLOCK - 1) / BLOCK;  // 1954 (covers tail rows too)

    kf_main<<<nblocks, BLOCK, 0, stream>>>(pred4, tgt4, out, partials, n);
    kf_reduce<<<1, 1024, 0, stream>>>(partials, out, nblocks, 1.0 / (double)n);
}

// Round 11
// 23.366 us; speedup vs baseline: 3.5122x; 1.0082x over previous
//
#include <hip/hip_runtime.h>

// KFIoU loss: per-row 5-float (x,y,w,h,r) pred/target -> smooth-L1 xy loss +
// KF IoU loss. Outputs: [loss.mean, xy_loss.mean, kf_loss.mean, KFIoU*3 (N)].
//
// R1: atomic storm fixed -> partials + reduce kernel.              (80us)
// R2/R4/R5/R10: load-shape & compute changes all plateau at 23-24;
//     R4==R2 falsifies the line-request theory.                    (22.8-24.4)
// R3: LDS staging via VGPR round trip regressed.                   (26.9us)
// R6-R9: single-kernel fusion abandoned (wbl2 storm / VGPR collapse
//     / memory-model race).
// R11: staging done RIGHT: __builtin_amdgcn_global_load_lds w=16 —
//     no data VGPRs, deep vmcnt-counted load queue, contiguous 1KB
//     chunks. 1024 rows/blk, 40KB LDS (4 blk/CU), stride-5 dword
//     LDS reads (2-way alias = free), rows tid+k*256 -> coalesced
//     dword stores. Partial last block takes direct-global path.

#define BLOCK 256
#define RPB   1024                    // rows per full block
#define BYTES_PT (RPB * 20)           // 20480 B per tensor per block

__device__ __forceinline__ void gload_lds16(const void* g, void* l) {
    __builtin_amdgcn_global_load_lds(
        (const __attribute__((address_space(1))) unsigned int*)g,
        (__attribute__((address_space(3))) unsigned int*)l,
        16, 0, 0);                    // size must be a literal 16
}

__device__ __forceinline__ void cov_terms(float w, float h, float r,
                                          float& s11, float& s12, float& s22,
                                          float& V) {
    w = fminf(fmaxf(w, 1e-7f), 1e7f);
    h = fminf(fmaxf(h, 1e-7f), 1e7f);
    const float sw = 0.25f * w * w;   // (0.5*w)^2
    const float sh = 0.25f * h * h;
    const float htr = 0.5f * (sw + sh);
    const float hdf = 0.5f * (sw - sh);
    // s11 = htr + cos(2r)*hdf ; s22 = htr - cos(2r)*hdf ; s12 = sin(2r)*hdf
    // hw trig computes sin(2*pi*x); 2r -> x = r/pi, |x|<=1.3: in range.
    const float x = r * 0.3183098861837907f;
    const float s2 = __builtin_amdgcn_sinf(x);
    const float c2 = __builtin_amdgcn_cosf(x);
    s11 = fmaf(c2, hdf, htr);
    s22 = fmaf(-c2, hdf, htr);
    s12 = s2 * hdf;
    V = w * h;
}

__device__ __forceinline__ float kf_row(const float* P, const float* T,
                                        float& xyl, float& kfl) {
    const float dx = fabsf(P[0] - T[0]);
    const float dy = fabsf(P[1] - T[1]);
    const float lx = dx < 1.0f ? 0.5f * dx * dx : dx - 0.5f;
    const float ly = dy < 1.0f ? 0.5f * dy * dy : dy - 0.5f;
    xyl = lx + ly;

    float ap, bp, dp, Vp, at, bt, dt, Vt;
    cov_terms(P[2], P[3], P[4], ap, bp, dp, Vp);
    cov_terms(T[2], T[3], T[4], at, bt, dt, Vt);

    // Sigma = Sp(Sp+St)^-1 St => detS = detSp*detSt/detSum, detSp=(Vp/4)^2
    // => Vb = 4*sqrt(detS) = 0.25*Vp*Vt*rsqrt(detSum)
    const float A = ap + at, B = bp + bt, D = dp + dt;
    const float detSum = fmaf(A, D, -B * B);
    const float Vb = (detSum > 0.0f)
                         ? 0.25f * Vp * Vt * __builtin_amdgcn_rsqf(detSum)
                         : 0.0f;
    const float kfiou = Vb * __builtin_amdgcn_rcpf(Vp + Vt - Vb + 1e-6f);
    kfl = 1.0f - kfiou;
    return 3.0f * kfiou;
}

__global__ __launch_bounds__(BLOCK) void kf_main(
    const float* __restrict__ pred, const float* __restrict__ tgt,
    float* __restrict__ out, float* __restrict__ partials, int n)
{
    __shared__ float sp_f[RPB * 5];   // 20 KB  (pred tile; [0..11] reused
    __shared__ float st_f[RPB * 5];   // 20 KB   for wave sums at the end)

    const int nfull = n / RPB;        // 1953 full blocks
    const int tid   = threadIdx.x;
    const int lane  = tid & 63;
    const int wave  = tid >> 6;
    float sl = 0.f, sx = 0.f, sk = 0.f;

    if (blockIdx.x < nfull) {
        // --- stage 2x20KB via global_load_lds: chunk (w*5+j) = 1KB,
        //     LDS dest wave-uniform base (HW adds lane*16), global per-lane.
        const char* pg = (const char*)pred + (size_t)blockIdx.x * BYTES_PT;
        const char* tg = (const char*)tgt  + (size_t)blockIdx.x * BYTES_PT;
#pragma unroll
        for (int j = 0; j < 5; ++j) {
            const int chunk = (wave * 5 + j) * 1024;
            gload_lds16(pg + chunk + lane * 16, (char*)sp_f + chunk);
            gload_lds16(tg + chunk + lane * 16, (char*)st_f + chunk);
        }
        __syncthreads();              // drains vmcnt; 4 blocks/CU overlap it

        const size_t base_row = (size_t)blockIdx.x * RPB;
#pragma unroll
        for (int k = 0; k < 4; ++k) {
            const int r = tid + k * BLOCK;       // stride-5 dword reads:
            float P[5], T[5];                    // 2-way bank alias = free
#pragma unroll
            for (int j = 0; j < 5; ++j) {
                P[j] = sp_f[5 * r + j];
                T[j] = st_f[5 * r + j];
            }
            float xyl, kfl;
            const float k3 = kf_row(P, T, xyl, kfl);
            out[3 + base_row + r] = k3;          // coalesced dword store
            sl += fmaxf(xyl + kfl, 0.f);
            sx += xyl;
            sk += kfl;
        }
    } else {
        // --- partial last block (n % RPB rows): direct-global path
        const int ri = nfull * RPB + tid;
        if (ri < n) {
            const float* p = pred + 5 * (size_t)ri;
            const float* q = tgt  + 5 * (size_t)ri;
            float P[5], T[5];
            __builtin_memcpy(P, p, 16);  P[4] = p[4];
            __builtin_memcpy(T, q, 16);  T[4] = q[4];
            float xyl, kfl;
            const float k3 = kf_row(P, T, xyl, kfl);
            out[3 + (size_t)ri] = k3;
            sl += fmaxf(xyl + kfl, 0.f);
            sx += xyl;
            sk += kfl;
        }
    }

    // wave64 tree reduce (fp32)
#pragma unroll
    for (int off = 32; off > 0; off >>= 1) {
        sl += __shfl_down(sl, off);
        sx += __shfl_down(sx, off);
        sk += __shfl_down(sk, off);
    }
    __syncthreads();                  // staging reads done before reuse
    if (lane == 0) {
        sp_f[wave] = sl; sp_f[4 + wave] = sx; sp_f[8 + wave] = sk;
    }
    __syncthreads();
    if (tid == 0) {
        float a = 0, b = 0, c = 0;
#pragma unroll
        for (int w = 0; w < 4; ++w) { a += sp_f[w]; b += sp_f[4 + w]; c += sp_f[8 + w]; }
        const int np = gridDim.x;     // plain stores; next dispatch sees them
        partials[blockIdx.x]          = a;
        partials[np + blockIdx.x]     = b;
        partials[2 * np + blockIdx.x] = c;
    }
}

__global__ __launch_bounds__(1024) void kf_reduce(
    const float* __restrict__ partials, float* __restrict__ out,
    int npart, double invn)
{
    double a = 0, b = 0, c = 0;
    for (int i = threadIdx.x; i < npart; i += 1024) {
        a += (double)partials[i];
        b += (double)partials[npart + i];
        c += (double)partials[2 * npart + i];
    }
#pragma unroll
    for (int off = 32; off > 0; off >>= 1) {
        a += __shfl_down(a, off);
        b += __shfl_down(b, off);
        c += __shfl_down(c, off);
    }
    __shared__ double smem[3][16];
    const int lane = threadIdx.x & 63;
    const int wave = threadIdx.x >> 6;
    if (lane == 0) {
        smem[0][wave] = a; smem[1][wave] = b; smem[2][wave] = c;
    }
    __syncthreads();
    if (threadIdx.x == 0) {
        double ra = 0, rb = 0, rc = 0;
#pragma unroll
        for (int w = 0; w < 16; ++w) { ra += smem[0][w]; rb += smem[1][w]; rc += smem[2][w]; }
        out[0] = (float)(ra * invn);
        out[1] = (float)(rb * invn);
        out[2] = (float)(rc * invn);
    }
}

extern "C" void kernel_launch(void* const* d_in, const int* in_sizes, int n_in,
                              void* d_out, int out_size, void* d_ws, size_t ws_size,
                              hipStream_t stream) {
    const float* pred = (const float*)d_in[0];
    const float* tgt  = (const float*)d_in[1];
    float* out = (float*)d_out;
    float* partials = (float*)d_ws;

    const int n = in_sizes[0] / 5;                   // 2,000,000
    const int nblocks = (n + RPB - 1) / RPB;         // 1954 (1953 full + tail)

    kf_main<<<nblocks, BLOCK, 0, stream>>>(pred, tgt, out, partials, n);
    kf_reduce<<<1, 1024, 0, stream>>>(partials, out, nblocks, 1.0 / (double)n);
}

// Round 12
// 22.814 us; speedup vs baseline: 3.5972x; 1.0242x over previous
//
#include <hip/hip_runtime.h>

// KFIoU loss: per-row 5-float (x,y,w,h,r) pred/target -> smooth-L1 xy loss +
// KF IoU loss. Outputs: [loss.mean, xy_loss.mean, kf_loss.mean, KFIoU*3 (N)].
//
// R1: atomic storm fixed -> partials + reduce kernel.              (80us)
// R2/R4/R5/R10/R11: five load-path structures (quad-f4, row-x4,
//     VGPR-LDS, gl_lds-LDS, nt) all 22.8-24.4 -> reads not lever.
// R6-R9: single-kernel fusion abandoned (wbl2 storm / VGPR collapse
//     / memory-model race at source level).
// R12: store side — quad form wrote 4 scattered dwords/thread (25%
//     wave-store density, ~2M store requests). Pack to ONE dwordx4
//     per thread (memcpy, 4B-aligned legal): 500k full-density
//     requests. nt hint dropped (cost ~0.8us in R10).

#define BLOCK 256

__device__ __forceinline__ void cov_terms(float w, float h, float r,
                                          float& s11, float& s12, float& s22,
                                          float& V) {
    w = fminf(fmaxf(w, 1e-7f), 1e7f);
    h = fminf(fmaxf(h, 1e-7f), 1e7f);
    const float sw = 0.25f * w * w;   // (0.5*w)^2
    const float sh = 0.25f * h * h;
    const float htr = 0.5f * (sw + sh);
    const float hdf = 0.5f * (sw - sh);
    // s11 = htr + cos(2r)*hdf ; s22 = htr - cos(2r)*hdf ; s12 = sin(2r)*hdf
    // hw trig computes sin(2*pi*x); 2r -> x = r/pi, |x|<=1.3: in range.
    const float x = r * 0.3183098861837907f;
    const float s2 = __builtin_amdgcn_sinf(x);
    const float c2 = __builtin_amdgcn_cosf(x);
    s11 = fmaf(c2, hdf, htr);
    s22 = fmaf(-c2, hdf, htr);
    s12 = s2 * hdf;
    V = w * h;
}

__device__ __forceinline__ float kf_row(const float* P, const float* T,
                                        float& xyl, float& kfl) {
    const float dx = fabsf(P[0] - T[0]);
    const float dy = fabsf(P[1] - T[1]);
    const float lx = dx < 1.0f ? 0.5f * dx * dx : dx - 0.5f;
    const float ly = dy < 1.0f ? 0.5f * dy * dy : dy - 0.5f;
    xyl = lx + ly;

    float ap, bp, dp, Vp, at, bt, dt, Vt;
    cov_terms(P[2], P[3], P[4], ap, bp, dp, Vp);
    cov_terms(T[2], T[3], T[4], at, bt, dt, Vt);

    // Sigma = Sp(Sp+St)^-1 St => detS = detSp*detSt/detSum, detSp=(Vp/4)^2
    // => Vb = 4*sqrt(detS) = 0.25*Vp*Vt*rsqrt(detSum)
    const float A = ap + at, B = bp + bt, D = dp + dt;
    const float detSum = fmaf(A, D, -B * B);
    const float Vb = (detSum > 0.0f)
                         ? 0.25f * Vp * Vt * __builtin_amdgcn_rsqf(detSum)
                         : 0.0f;
    const float kfiou = Vb * __builtin_amdgcn_rcpf(Vp + Vt - Vb + 1e-6f);
    kfl = 1.0f - kfiou;
    return 3.0f * kfiou;
}

__global__ __launch_bounds__(BLOCK) void kf_main(
    const float4* __restrict__ pred4, const float4* __restrict__ tgt4,
    float* __restrict__ out, float* __restrict__ partials, int n)
{
    const int n4 = n >> 2;                       // row-quads
    const int t  = blockIdx.x * BLOCK + threadIdx.x;
    float sl = 0.f, sx = 0.f, sk = 0.f;

    if (t < n4) {
        // straight-line: 10 independent float4 loads issued before any use
        float P[20], T[20];
        const float4* p4 = pred4 + 5 * (size_t)t;
        const float4* t4 = tgt4  + 5 * (size_t)t;
#pragma unroll
        for (int j = 0; j < 5; ++j) reinterpret_cast<float4*>(P)[j] = p4[j];
#pragma unroll
        for (int j = 0; j < 5; ++j) reinterpret_cast<float4*>(T)[j] = t4[j];

        float vals[4];
#pragma unroll
        for (int k = 0; k < 4; ++k) {
            float xyl, kfl;
            vals[k] = kf_row(P + 5 * k, T + 5 * k, xyl, kfl);
            sl += fmaxf(xyl + kfl, 0.f);
            sx += xyl;
            sk += kfl;
        }
        // ONE dwordx4 store per thread (4B-aligned OK): full-density waves
        __builtin_memcpy(&out[3 + 4 * (size_t)t], vals, 16);
    }
    // leftover rows (n % 4) — dead for N=2M, kept for generality
    const int ri = (n4 << 2) + t;
    if (ri < n) {
        const float* p = (const float*)pred4 + 5 * (size_t)ri;
        const float* q = (const float*)tgt4  + 5 * (size_t)ri;
        float P[5], T[5];
#pragma unroll
        for (int j = 0; j < 5; ++j) { P[j] = p[j]; T[j] = q[j]; }
        float xyl, kfl;
        const float k3 = kf_row(P, T, xyl, kfl);
        out[3 + (size_t)ri] = k3;
        sl += fmaxf(xyl + kfl, 0.f);
        sx += xyl;
        sk += kfl;
    }

    // wave64 tree reduce (fp32)
#pragma unroll
    for (int off = 32; off > 0; off >>= 1) {
        sl += __shfl_down(sl, off);
        sx += __shfl_down(sx, off);
        sk += __shfl_down(sk, off);
    }
    __shared__ float smem[3][4];
    const int lane = threadIdx.x & 63;
    const int wave = threadIdx.x >> 6;
    if (lane == 0) {
        smem[0][wave] = sl; smem[1][wave] = sx; smem[2][wave] = sk;
    }
    __syncthreads();
    if (threadIdx.x == 0) {
        float a = 0, b = 0, c = 0;
#pragma unroll
        for (int w = 0; w < 4; ++w) { a += smem[0][w]; b += smem[1][w]; c += smem[2][w]; }
        const int np = gridDim.x;                // plain stores; next dispatch
        partials[blockIdx.x]          = a;       // sees them (stream ordering)
        partials[np + blockIdx.x]     = b;
        partials[2 * np + blockIdx.x] = c;
    }
}

__global__ __launch_bounds__(1024) void kf_reduce(
    const float* __restrict__ partials, float* __restrict__ out,
    int npart, double invn)
{
    double a = 0, b = 0, c = 0;
    for (int i = threadIdx.x; i < npart; i += 1024) {
        a += (double)partials[i];
        b += (double)partials[npart + i];
        c += (double)partials[2 * npart + i];
    }
#pragma unroll
    for (int off = 32; off > 0; off >>= 1) {
        a += __shfl_down(a, off);
        b += __shfl_down(b, off);
        c += __shfl_down(c, off);
    }
    __shared__ double smem[3][16];
    const int lane = threadIdx.x & 63;
    const int wave = threadIdx.x >> 6;
    if (lane == 0) {
        smem[0][wave] = a; smem[1][wave] = b; smem[2][wave] = c;
    }
    __syncthreads();
    if (threadIdx.x == 0) {
        double ra = 0, rb = 0, rc = 0;
#pragma unroll
        for (int w = 0; w < 16; ++w) { ra += smem[0][w]; rb += smem[1][w]; rc += smem[2][w]; }
        out[0] = (float)(ra * invn);
        out[1] = (float)(rb * invn);
        out[2] = (float)(rc * invn);
    }
}

extern "C" void kernel_launch(void* const* d_in, const int* in_sizes, int n_in,
                              void* d_out, int out_size, void* d_ws, size_t ws_size,
                              hipStream_t stream) {
    const float4* pred4 = (const float4*)d_in[0];
    const float4* tgt4  = (const float4*)d_in[1];
    float* out = (float*)d_out;
    float* partials = (float*)d_ws;

    const int n  = in_sizes[0] / 5;                // 2,000,000
    const int n4 = n >> 2;                         // 500,000
    const int nblocks = (n4 + BLOCK - 1) / BLOCK;  // 1954

    kf_main<<<nblocks, BLOCK, 0, stream>>>(pred4, tgt4, out, partials, n);
    kf_reduce<<<1, 1024, 0, stream>>>(partials, out, nblocks, 1.0 / (double)n);
}